// Round 10
// baseline (145.708 us; speedup 1.0000x reference)
//
#include <hip/hip_runtime.h>

// EigenPro forward: out[8192,10] = exp(-GAMMA * d2(x, centers)) @ weight
// x [8192,128] f32, centers [50000,128] f32, weight [50000,10] f32.
//
// Factorization: exp(-g*d2) = exp2(2g'*x.c) * exp2(-g'*|c|^2) * exp2(-g'*|x|^2)
//   - 2g' baked into bf16 center image (precompute)
//   - exp2(-g'*|c|^2) baked into bf16 W' fragment image (precompute)
//   - exp2(-g'*|x|^2) applied as final f32 row scale (exact)
//
// r10: r9 structure with ALL s_setprio removed and minimal sched fences --
//      one straight-line region per tile so the scheduler can interleave
//      pack (exp2/cvtpk, TRANS/VALU pipes) into MFMA issue shadows.

#define NX 8192
#define NC 50000
#define DD 128
#define NO 10
#define BN 64
#define NTILES 782                                   // ceil(50000/64)
#define NCHUNK 24
#define MBLKS 32                                     // 8192 / 256
#define GRID_MAIN (MBLKS * NCHUNK)                   // 768

#define GAMMA 0.02f
#define LOG2E 1.4426950408889634f
#define GLOG2E (GAMMA * LOG2E)
#define S2G (2.0f * GAMMA * LOG2E)

// ws image layout (bytes)
#define OFF_XIMG 0ull
#define OFF_CIMG 2097152ull          // 256 x-frag groups * 8192
#define OFF_WIMG 14909440ull         // + 782 cent-tiles * 16384
#define OFF_XSC  18112512ull         // + 782 W'-frag tiles * 4096
#define WS_NEED  18145280ull         // + 8192 * 4

typedef __attribute__((ext_vector_type(8))) short short8;
typedef __attribute__((ext_vector_type(4))) float f32x4;
typedef __attribute__((ext_vector_type(16))) float f32x16;

__device__ __forceinline__ unsigned pk_bf16(float a, float b) {
  union { float f; unsigned u; } ua, ub;
  ua.f = a; ub.f = b;
  unsigned ha = (ua.u + 0x7FFFu + ((ua.u >> 16) & 1u)) >> 16;
  unsigned hb = (ub.u + 0x7FFFu + ((ub.u >> 16) & 1u)) >> 16;
  return (hb << 16) | (ha & 0xFFFFu);
}
__device__ __forceinline__ unsigned short bf16_1(float a) {
  union { float f; unsigned u; } ua;
  ua.f = a;
  return (unsigned short)((ua.u + 0x7FFFu + ((ua.u >> 16) & 1u)) >> 16);
}

// ---------------- fused precompute kernel -----------------------------------
// blocks 0..63: x fragment image (lane-major MFMA B-frag order) + x row scales
// blocks 64..845: center tile image (swizzled, pre-scaled) + W' fragment image

__global__ void pre_all(const float* __restrict__ x, const float* __restrict__ cent,
                        const float* __restrict__ w, char* __restrict__ ws) {
  const int b = blockIdx.x, t = threadIdx.x;
  if (b < 64) {
    // x fragment image, linear in frag-group f = m-row/32:
    // addr = f*8192 + ks*1024 + lane*16
    // lane l of group f holds x[f*32 + (l&31)][ks*16 + (l>>5)*8 + 0..7]
    char* img = ws + OFF_XIMG + (size_t)b * 32768;
#pragma unroll
    for (int i = 0; i < 8; ++i) {
      int e = i * 256 + t;
      int wv = e >> 9, ks = (e >> 6) & 7, l = e & 63;
      int m = b * 128 + wv * 32 + (l & 31);
      int k0 = ks * 16 + (l >> 5) * 8;
      const float4 v0 = *(const float4*)(x + (size_t)m * DD + k0);
      const float4 v1 = *(const float4*)(x + (size_t)m * DD + k0 + 4);
      uint4 pk;
      pk.x = pk_bf16(v0.x, v0.y);
      pk.y = pk_bf16(v0.z, v0.w);
      pk.z = pk_bf16(v1.x, v1.y);
      pk.w = pk_bf16(v1.z, v1.w);
      *(uint4*)(img + e * 16) = pk;
    }
    if (t < 128) {
      const int m = b * 128 + t;
      const float4* r4 = (const float4*)(x + (size_t)m * DD);
      float s = 0.f;
#pragma unroll
      for (int k = 0; k < 32; ++k) {
        float4 v = r4[k];
        s += v.x * v.x + v.y * v.y + v.z * v.z + v.w * v.w;
      }
      ((float*)(ws + OFF_XSC))[m] = __builtin_amdgcn_exp2f(-GLOG2E * s);
    }
  } else {
    const int tile = b - 64;
    __shared__ float sNF[BN];
    // phase 1: center norm factors, 4 threads per center + shfl reduce
    {
      const int c_loc = t >> 2;    // 0..63
      const int part = t & 3;      // quarter-row
      const int c = tile * BN + c_loc;
      float s = 0.f;
      if (c < NC) {
        const float4* r4 = (const float4*)(cent + (size_t)c * DD) + part * 8;
#pragma unroll
        for (int k = 0; k < 8; ++k) {
          float4 v = r4[k];
          s += v.x * v.x + v.y * v.y + v.z * v.z + v.w * v.w;
        }
      }
      s += __shfl_xor(s, 1);
      s += __shfl_xor(s, 2);
      if (part == 0) sNF[c_loc] = __builtin_amdgcn_exp2f(-GLOG2E * s);
    }
    __syncthreads();

    // center image: 64 rows x 256 B, 16-slot XOR swizzle, scaled by S2G
    {
      char* img = ws + OFF_CIMG + (size_t)tile * 16384;
      const int col4 = t & 31, rb = t >> 5;
#pragma unroll
      for (int i = 0; i < 8; ++i) {
        int row = rb + 8 * i;  // 0..63
        int c = tile * BN + row;
        float4 v = make_float4(0.f, 0.f, 0.f, 0.f);
        if (c < NC) v = *(const float4*)(cent + (size_t)c * DD + col4 * 4);
        uint2 pk;
        pk.x = pk_bf16(S2G * v.x, S2G * v.y);
        pk.y = pk_bf16(S2G * v.z, S2G * v.w);
        *(uint2*)(img + row * 256 + ((col4 * 8) ^ ((row & 15) << 4))) = pk;
      }
    }

    // W' fragments, lane-major: group gg covers c-local gg*16..+15;
    // lane l (j=l&31, hi=l>>5) holds W'[j][gg*16 + hi*8 + 0..7]
    {
      const int l = t & 63, gg = t >> 6;
      const int j = l & 31, hi = l >> 5;
      const int clbase = gg * 16 + hi * 8;
      unsigned d[4];
#pragma unroll
      for (int i = 0; i < 4; ++i) {
        int cl0 = clbase + 2 * i;
        int c0 = tile * BN + cl0;
        float w0 = 0.f, w1 = 0.f;
        if (j < NO) {
          if (c0 < NC) w0 = w[(size_t)c0 * NO + j] * sNF[cl0];
          if (c0 + 1 < NC) w1 = w[(size_t)(c0 + 1) * NO + j] * sNF[cl0 + 1];
        }
        d[i] = pk_bf16(w0, w1);
      }
      *(uint4*)(ws + OFF_WIMG + (size_t)tile * 4096 + t * 16) =
          make_uint4(d[0], d[1], d[2], d[3]);
    }
  }
}

// ---------------- main MFMA kernel ------------------------------------------

__device__ __forceinline__ short8 ld_frag16(const short* base, int row, int kbyte) {
  const char* p = (const char*)base + row * 256 + (kbyte ^ ((row & 15) << 4));
  return *(const short8*)p;
}

__device__ __forceinline__ void gld16(const char* g, const char* l) {
  __builtin_amdgcn_global_load_lds(
      (const __attribute__((address_space(1))) unsigned int*)g,
      (__attribute__((address_space(3))) unsigned int*)l, 16, 0, 0);
}

// raw global->register 16B load; vmcnt managed manually
__device__ __forceinline__ short8 gload16(const char* p) {
  short8 r;
  asm volatile("global_load_dwordx4 %0, %1, off" : "=v"(r) : "v"(p));
  return r;
}

__device__ __forceinline__ unsigned cvtpk(float lo, float hi2) {
  unsigned r;
  asm volatile("v_cvt_pk_bf16_f32 %0, %1, %2" : "=v"(r) : "v"(lo), "v"(hi2));
  return r;
}
__device__ __forceinline__ void swap32(unsigned& a, unsigned& b) {
  asm volatile("v_permlane32_swap_b32 %0, %1" : "+v"(a), "+v"(b));
}
__device__ __forceinline__ short8 mk8(unsigned a, unsigned b, unsigned c, unsigned d) {
  union { unsigned u[4]; short8 s; } z;
  z.u[0] = a; z.u[1] = b; z.u[2] = c; z.u[3] = d;
  return z.s;
}

// exp2 + pack + permlane: acc (32x32 S^T quadrant, this lane = 16 elems)
// -> two PV A-fragments: pE (c-local 0..15), pO (c-local 16..31)
__device__ __forceinline__ void pack32(const f32x16 acc, short8& pE, short8& pO) {
  float p[16];
#pragma unroll
  for (int r = 0; r < 16; ++r) p[r] = __builtin_amdgcn_exp2f(acc[r]);
  unsigned a0 = cvtpk(p[0], p[1]);
  unsigned a1 = cvtpk(p[2], p[3]);
  unsigned a2 = cvtpk(p[4], p[5]);
  unsigned a3 = cvtpk(p[6], p[7]);
  unsigned b0 = cvtpk(p[8], p[9]);
  unsigned b1 = cvtpk(p[10], p[11]);
  unsigned b2 = cvtpk(p[12], p[13]);
  unsigned b3 = cvtpk(p[14], p[15]);
  swap32(a0, a2);
  swap32(a1, a3);
  swap32(b0, b2);
  swap32(b1, b3);
  pE = mk8(a0, a1, a2, a3);
  pO = mk8(b0, b1, b2, b3);
}

__global__ void __launch_bounds__(256, 3) eigenpro_mfma(
    const char* __restrict__ ws, float* __restrict__ out) {
  __shared__ short sB[3][8192];  // 3 x 16 KB center tile (48 KB total)

  const int t = threadIdx.x;
  const int lane = t & 63;
  const int wid = t >> 6;
  const int l31 = lane & 31;
  const int hi = lane >> 5;
  const int hib = hi * 16;

  const int chunk = blockIdx.x % NCHUNK;
  const int mb = blockIdx.x / NCHUNK;

  const char* cimg = ws + OFF_CIMG;
  const char* wimg = ws + OFF_WIMG;
  const float* xs = (const float*)(ws + OFF_XSC);

  // 782 = 14*33 + 10*32
  const int t0 = chunk * 32 + (chunk < 14 ? chunk : 14);
  const int nt = 32 + (chunk < 14 ? 1 : 0);

  // prologue: x fragments for 2 m-frags (16 gloads), then first tile DMA (4)
  short8 xf[2][8];
#pragma unroll
  for (int mf = 0; mf < 2; ++mf) {
    const char* xg =
        ws + OFF_XIMG + (size_t)(mb * 8 + wid * 2 + mf) * 8192 + lane * 16;
#pragma unroll
    for (int ks = 0; ks < 8; ++ks) xf[mf][ks] = gload16(xg + ks * 1024);
  }
  __builtin_amdgcn_sched_barrier(0);
  {
    const char* cg = cimg + (size_t)t0 * 16384 + wid * 4096 + lane * 16;
    const char* cl = (const char*)&sB[0][0] + wid * 4096;
#pragma unroll
    for (int i = 0; i < 4; ++i) gld16(cg + i * 1024, cl + i * 1024);
  }
  asm volatile("s_waitcnt vmcnt(4)" ::: "memory");  // xf ready; tile-0 DMA rolls
  __builtin_amdgcn_sched_barrier(0);

  const f32x16 zero16 = {0.f, 0.f, 0.f, 0.f, 0.f, 0.f, 0.f, 0.f,
                         0.f, 0.f, 0.f, 0.f, 0.f, 0.f, 0.f, 0.f};
  f32x16 pv0 = zero16, pv1 = zero16;

  int cur = 0;
#pragma unroll 1
  for (int it = 0; it < nt; ++it) {
    const int nxt = (cur == 2) ? 0 : cur + 1;
    const short* Bt = &sB[cur][0];

    // W'(cur tile) -> regs, issued FIRST (FIFO: retires before next-tile DMA)
    const char* wg = wimg + (size_t)(t0 + it) * 4096 + lane * 16;
    short8 wfr[4];
    wfr[0] = gload16(wg);
    wfr[1] = gload16(wg + 1024);
    wfr[2] = gload16(wg + 2048);
    wfr[3] = gload16(wg + 3072);
    __builtin_amdgcn_sched_barrier(0);  // pin W-before-DMA issue order (vmcnt FIFO)

    const int has_next = (it + 1 < nt);
    if (has_next) {
      // write target sB[nxt]: any wave still computing is at worst on tile
      // it-1 reading sB[cur-1 mod 3] != sB[nxt]  -> no barrier needed here
      const char* cg = cimg + (size_t)(t0 + it + 1) * 16384 + wid * 4096 + lane * 16;
      const char* cl = (const char*)&sB[nxt][0] + wid * 4096;
#pragma unroll
      for (int i = 0; i < 4; ++i) gld16(cg + i * 1024, cl + i * 1024);
      asm volatile("s_waitcnt vmcnt(8)" ::: "memory");  // cur-tile DMA done
    } else {
      asm volatile("s_waitcnt vmcnt(4)" ::: "memory");
    }
    __builtin_amdgcn_s_barrier();  // cur tile staged for all waves
    __builtin_amdgcn_sched_barrier(0);  // no LDS-read hoist above barrier

#pragma unroll
    for (int ct = 0; ct < 2; ++ct) {
      // QK^T (S^T orientation): one center read feeds BOTH m-frags
      f32x16 acc0 = zero16, acc1 = zero16;
#pragma unroll
      for (int ks = 0; ks < 8; ++ks) {
        short8 ca = ld_frag16(Bt, ct * 32 + l31, ks * 32 + hib);
        acc0 = __builtin_amdgcn_mfma_f32_32x32x16_bf16(ca, xf[0][ks], acc0, 0, 0, 0);
        acc1 = __builtin_amdgcn_mfma_f32_32x32x16_bf16(ca, xf[1][ks], acc1, 0, 0, 0);
      }

      short8 paE0, paO0, paE1, paO1;
      pack32(acc0, paE0, paO0);
      pack32(acc1, paE1, paO1);

      if (ct == 0) {
        if (has_next) {
          asm volatile("s_waitcnt vmcnt(4)" ::: "memory");  // all 4 W frags ready
        } else {
          asm volatile("s_waitcnt vmcnt(0)" ::: "memory");
        }
        __builtin_amdgcn_sched_barrier(0);  // rule-18: no wfr-use hoist above wait
      }
      pv0 = __builtin_amdgcn_mfma_f32_32x32x16_bf16(paE0, wfr[2 * ct], pv0, 0, 0, 0);
      pv1 = __builtin_amdgcn_mfma_f32_32x32x16_bf16(paE1, wfr[2 * ct], pv1, 0, 0, 0);
      pv0 = __builtin_amdgcn_mfma_f32_32x32x16_bf16(paO0, wfr[2 * ct + 1], pv0, 0, 0, 0);
      pv1 = __builtin_amdgcn_mfma_f32_32x32x16_bf16(paO1, wfr[2 * ct + 1], pv1, 0, 0, 0);
    }
    cur = nxt;
  }

  // epilogue: out[m][j] += pv * exp2(-g'*|x_m|^2)
  if (l31 < NO) {
#pragma unroll
    for (int r = 0; r < 16; ++r) {
      int mloc = (r & 3) + 8 * (r >> 2) + 4 * hi;
      int m0 = mb * 256 + wid * 64 + mloc;
      atomicAdd(&out[(size_t)m0 * NO + l31], pv0[r] * xs[m0]);
      atomicAdd(&out[(size_t)(m0 + 32) * NO + l31], pv1[r] * xs[m0 + 32]);
    }
  }
}

// ---------------- fallback path (round-1, passing) --------------------------

__global__ void eigenpro_sqnorm(const float* __restrict__ x,
                                const float* __restrict__ cent,
                                float* __restrict__ ws) {
  int i = blockIdx.x * blockDim.x + threadIdx.x;
  if (i >= NX + NC) return;
  const float* row = (i < NX) ? (x + (size_t)i * DD) : (cent + (size_t)(i - NX) * DD);
  const float4* r4 = (const float4*)row;
  float s = 0.f;
#pragma unroll
  for (int k = 0; k < DD / 4; ++k) {
    float4 v = r4[k];
    s += v.x * v.x + v.y * v.y + v.z * v.z + v.w * v.w;
  }
  ws[i] = -GLOG2E * s;
}

__device__ __forceinline__ void stage_tile8(const float* __restrict__ src, int nrows,
                                            short* dst, int t) {
  int col4 = t & 31;
  int rb = t >> 5;
#pragma unroll
  for (int i = 0; i < 16; ++i) {
    int row = rb + 8 * i;
    float4 v = make_float4(0.f, 0.f, 0.f, 0.f);
    if (row < nrows) v = *(const float4*)(src + (size_t)row * DD + col4 * 4);
    unsigned lo = pk_bf16(v.x, v.y), hi = pk_bf16(v.z, v.w);
    char* p = (char*)dst + row * 256 + ((col4 * 8) ^ ((row & 7) << 4));
    *(uint2*)p = make_uint2(lo, hi);
  }
}

__device__ __forceinline__ short8 ld_frag8(const short* base, int row, int kbyte) {
  const char* p = (const char*)base + row * 256 + (kbyte ^ ((row & 7) << 4));
  return *(const short8*)p;
}

__global__ void __launch_bounds__(256, 2) eigenpro_main_fb(
    const float* __restrict__ x, const float* __restrict__ cent,
    const float* __restrict__ w, const float* __restrict__ ws2,
    float* __restrict__ out) {
  __shared__ short sA[128 * DD];
  __shared__ short sBP[128 * DD];
  __shared__ short sWt[16 * 128];
  __shared__ float sC2[128];

  const int t = threadIdx.x;
  const int lane = t & 63;
  const int wid = t >> 6;
  const int l15 = lane & 15;
  const int g = lane >> 4;

  const int chunk = blockIdx.x & 7;
  const int mb = blockIdx.x >> 3;
  const int m0 = mb * 128;
  const int wrow0 = wid * 32;

  const float* ws_x2 = ws2;
  const float* ws_c2 = ws2 + NX;

  stage_tile8(x + (size_t)m0 * DD, 128, sA, t);

  float u[2][4];
#pragma unroll
  for (int mf = 0; mf < 2; ++mf)
#pragma unroll
    for (int r = 0; r < 4; ++r)
      u[mf][r] = ws_x2[m0 + wrow0 + mf * 16 + 4 * g + r];

  const f32x4 zero4 = {0.f, 0.f, 0.f, 0.f};
  f32x4 pv[2];
  pv[0] = zero4;
  pv[1] = zero4;

  const int nt128 = 391;
  const int tp = 49;
  const int t0 = chunk * tp;
  const int t1 = (t0 + tp < nt128) ? (t0 + tp) : nt128;

  for (int tile = t0; tile < t1; ++tile) {
    const int c0 = tile * 128;
    int nrows = NC - c0; if (nrows > 128) nrows = 128;

    __syncthreads();
    stage_tile8(cent + (size_t)c0 * DD, nrows, sBP, t);
    if (t < 128) {
      int c = c0 + t;
      sC2[t] = (c < NC) ? ws_c2[c] : -3.0e38f;
      float wrow[NO];
#pragma unroll
      for (int j = 0; j < NO; ++j) wrow[j] = (c < NC) ? w[(size_t)c * NO + j] : 0.f;
#pragma unroll
      for (int j = 0; j < 16; ++j) {
        unsigned short h = (j < NO && c < NC) ? bf16_1(wrow[j]) : (unsigned short)0;
        *(short*)((char*)sWt + j * 256 + ((2 * t) ^ ((j & 7) << 4))) = (short)h;
      }
    }
    __syncthreads();

    float v[8];
#pragma unroll
    for (int nf = 0; nf < 8; ++nf) v[nf] = sC2[nf * 16 + l15];

    short8 a[2][4];
#pragma unroll
    for (int mf = 0; mf < 2; ++mf)
#pragma unroll
      for (int ks = 0; ks < 4; ++ks)
        a[mf][ks] = ld_frag8(sA, wrow0 + mf * 16 + l15, ks * 64 + g * 16);

    f32x4 acc[2][8];
#pragma unroll
    for (int mf = 0; mf < 2; ++mf)
#pragma unroll
      for (int nf = 0; nf < 8; ++nf) acc[mf][nf] = zero4;

#pragma unroll
    for (int nf = 0; nf < 8; ++nf) {
#pragma unroll
      for (int ks = 0; ks < 4; ++ks) {
        short8 b = ld_frag8(sBP, nf * 16 + l15, ks * 64 + g * 16);
        acc[0][nf] = __builtin_amdgcn_mfma_f32_16x16x32_bf16(a[0][ks], b, acc[0][nf], 0, 0, 0);
        acc[1][nf] = __builtin_amdgcn_mfma_f32_16x16x32_bf16(a[1][ks], b, acc[1][nf], 0, 0, 0);
      }
    }

    __syncthreads();

#pragma unroll
    for (int mf = 0; mf < 2; ++mf) {
#pragma unroll
      for (int nf = 0; nf < 8; ++nf) {
#pragma unroll
        for (int r = 0; r < 4; ++r) {
          float s = acc[mf][nf][r];
          float arg = fmaf(s, 2.f * GAMMA * LOG2E, u[mf][r] + v[nf]);
          arg = fminf(arg, 0.f);
          float p = __builtin_amdgcn_exp2f(arg);
          int mrow = wrow0 + mf * 16 + 4 * g + r;
          *(short*)((char*)sBP + mrow * 256 + ((2 * (nf * 16 + l15)) ^ ((mrow & 7) << 4))) =
              (short)bf16_1(p);
        }
      }
    }
    __syncthreads();

#pragma unroll
    for (int ks = 0; ks < 4; ++ks) {
      short8 bw = ld_frag8(sWt, l15, ks * 64 + g * 16);
#pragma unroll
      for (int mf = 0; mf < 2; ++mf) {
        short8 pa = ld_frag8(sBP, wrow0 + mf * 16 + l15, ks * 64 + g * 16);
        pv[mf] = __builtin_amdgcn_mfma_f32_16x16x32_bf16(pa, bw, pv[mf], 0, 0, 0);
      }
    }
  }

  if (l15 < NO) {
#pragma unroll
    for (int mf = 0; mf < 2; ++mf) {
#pragma unroll
      for (int r = 0; r < 4; ++r) {
        int m = m0 + wrow0 + mf * 16 + 4 * g + r;
        atomicAdd(&out[(size_t)m * NO + l15], pv[mf][r]);
      }
    }
  }
}

// ---------------- launch ----------------------------------------------------

extern "C" void kernel_launch(void* const* d_in, const int* in_sizes, int n_in,
                              void* d_out, int out_size, void* d_ws, size_t ws_size,
                              hipStream_t stream) {
  const float* x = (const float*)d_in[0];
  const float* cent = (const float*)d_in[1];
  const float* w = (const float*)d_in[2];
  float* out = (float*)d_out;

  hipMemsetAsync(d_out, 0, (size_t)out_size * sizeof(float), stream);

  if (ws_size >= WS_NEED) {
    pre_all<<<64 + NTILES, 256, 0, stream>>>(x, cent, w, (char*)d_ws);
    eigenpro_mfma<<<GRID_MAIN, 256, 0, stream>>>((const char*)d_ws, out);
  } else {
    float* ws = (float*)d_ws;
    int nrows = NX + NC;
    eigenpro_sqnorm<<<(nrows + 255) / 256, 256, 0, stream>>>(x, cent, ws);
    eigenpro_main_fb<<<64 * 8, 256, 0, stream>>>(x, cent, w, ws, out);
  }
}

// Round 11
// 98.668 us; speedup vs baseline: 1.4768x; 1.4768x over previous
//
#include <hip/hip_runtime.h>
#include <hip/hip_fp8.h>

// EigenPro forward: out[8192,10] = exp(-GAMMA * d2(x, centers)) @ weight
// x [8192,128] f32, centers [50000,128] f32, weight [50000,10] f32.
//
// Factorization: exp(-g*d2) = exp2(2g'*x.c) * exp2(-g'*|c|^2) * exp2(-g'*|x|^2)
//   r11: QK via MX-FP8 mfma_scale 32x32x64 (2x rate, half LDS bytes).
//   - centers stored raw e4m3; x stored e4m3 scaled by 2g'log2e*16 = 0.923
//   - MFMA scale_b = 2^-4 (E8M0 0x7B) makes the 2g'log2e fold EXACT
//   - exp2(-g'*|c|^2) baked into bf16 W' fragment image; PV stays bf16
//   - exp2(-g'*|x|^2) applied as final f32 row scale (exact)

#define NX 8192
#define NC 50000
#define DD 128
#define NO 10
#define BN 64
#define NTILES 782                                   // ceil(50000/64)
#define NCHUNK 24
#define MBLKS 32                                     // 8192 / 256
#define GRID_MAIN (MBLKS * NCHUNK)                   // 768

#define GAMMA 0.02f
#define LOG2E 1.4426950408889634f
#define GLOG2E (GAMMA * LOG2E)
#define S2G (2.0f * GAMMA * LOG2E)
#define XSCALE (S2G * 16.0f)                         // 0.92332... (scale_b = 2^-4)
#define SCALE_ONE 0x7F7F7F7Fu                        // E8M0 1.0 in every byte
#define SCALE_B16 0x7B7B7B7Bu                        // E8M0 2^-4 in every byte

// ws image layout (bytes)
#define OFF_XIMG 0ull                 // 256 groups * 4096   = 1,048,576
#define OFF_XSC  1048576ull           // 8192 * 4            -> 1,081,344
#define OFF_CIMG 1081344ull           // 782 tiles * 8192    -> 7,487,488
#define OFF_WIMG 7487488ull           // 782 tiles * 4096    -> 10,690,560
#define WS_NEED  10690560ull

typedef __attribute__((ext_vector_type(8))) short short8;
typedef __attribute__((ext_vector_type(4))) float f32x4;
typedef __attribute__((ext_vector_type(16))) float f32x16;
typedef __attribute__((ext_vector_type(4))) int i32x4;
typedef __attribute__((ext_vector_type(8))) int i32x8;

__device__ __forceinline__ unsigned pk_bf16(float a, float b) {
  union { float f; unsigned u; } ua, ub;
  ua.f = a; ub.f = b;
  unsigned ha = (ua.u + 0x7FFFu + ((ua.u >> 16) & 1u)) >> 16;
  unsigned hb = (ub.u + 0x7FFFu + ((ub.u >> 16) & 1u)) >> 16;
  return (hb << 16) | (ha & 0xFFFFu);
}
__device__ __forceinline__ unsigned short bf16_1(float a) {
  union { float f; unsigned u; } ua;
  ua.f = a;
  return (unsigned short)((ua.u + 0x7FFFu + ((ua.u >> 16) & 1u)) >> 16);
}
__device__ __forceinline__ unsigned char to_fp8(float v) {
  return (unsigned char)__hip_cvt_float_to_fp8(v, __HIP_SATFINITE, __HIP_E4M3);
}
// pack 16 floats (scaled) -> uint4 of e4m3 bytes
__device__ __forceinline__ uint4 fp8x16(const float* v, float s) {
  unsigned w[4];
#pragma unroll
  for (int i = 0; i < 4; ++i) {
    w[i] = (unsigned)to_fp8(s * v[4 * i + 0]) |
           ((unsigned)to_fp8(s * v[4 * i + 1]) << 8) |
           ((unsigned)to_fp8(s * v[4 * i + 2]) << 16) |
           ((unsigned)to_fp8(s * v[4 * i + 3]) << 24);
  }
  return make_uint4(w[0], w[1], w[2], w[3]);
}

// ---------------- fused precompute kernel -----------------------------------
// blocks 0..63: x fp8 fragment image + x row scales
// blocks 64..845: center fp8 fragment image + W' bf16 fragment image
//
// Fragment layout (per 32-row group, B/A symmetric): lane l holds
// elem[k = (l>>5)*32 + half*16 + 0..15] of row (l&31); chunk address =
// fid*1024 + lane*16 with fid = (ks2*2+half) [x] or ((ct*2+ks2)*2+half) [cent].

__global__ void pre_all(const float* __restrict__ x, const float* __restrict__ cent,
                        const float* __restrict__ w, char* __restrict__ ws) {
  const int b = blockIdx.x, t = threadIdx.x;
  if (b < 64) {
    char* img = ws + OFF_XIMG + (size_t)b * 16384;  // 4 groups * 4096
#pragma unroll
    for (int i = 0; i < 4; ++i) {
      int q = i * 256 + t;            // 0..1023
      int g_local = q >> 8;           // 0..3
      int r = q & 255;
      int fid = r >> 6;               // 0..3 = ks2*2+half
      int lane = r & 63;
      int ks2 = fid >> 1, half = fid & 1;
      int m = b * 128 + g_local * 32 + (lane & 31);
      int k0 = ks2 * 64 + (lane >> 5) * 32 + half * 16;
      float v[16];
      *(float4*)&v[0] = *(const float4*)(x + (size_t)m * DD + k0);
      *(float4*)&v[4] = *(const float4*)(x + (size_t)m * DD + k0 + 4);
      *(float4*)&v[8] = *(const float4*)(x + (size_t)m * DD + k0 + 8);
      *(float4*)&v[12] = *(const float4*)(x + (size_t)m * DD + k0 + 12);
      *(uint4*)(img + g_local * 4096 + fid * 1024 + lane * 16) = fp8x16(v, XSCALE);
    }
    if (t < 128) {
      const int m = b * 128 + t;
      const float4* r4 = (const float4*)(x + (size_t)m * DD);
      float s = 0.f;
#pragma unroll
      for (int k = 0; k < 32; ++k) {
        float4 v = r4[k];
        s += v.x * v.x + v.y * v.y + v.z * v.z + v.w * v.w;
      }
      ((float*)(ws + OFF_XSC))[m] = __builtin_amdgcn_exp2f(-GLOG2E * s);
    }
  } else {
    const int tile = b - 64;
    __shared__ float sNF[BN];
    // center norm factors: 4 threads per center + shfl reduce
    {
      const int c_loc = t >> 2;
      const int part = t & 3;
      const int c = tile * BN + c_loc;
      float s = 0.f;
      if (c < NC) {
        const float4* r4 = (const float4*)(cent + (size_t)c * DD) + part * 8;
#pragma unroll
        for (int k = 0; k < 8; ++k) {
          float4 v = r4[k];
          s += v.x * v.x + v.y * v.y + v.z * v.z + v.w * v.w;
        }
      }
      s += __shfl_xor(s, 1);
      s += __shfl_xor(s, 2);
      if (part == 0) sNF[c_loc] = __builtin_amdgcn_exp2f(-GLOG2E * s);
    }
    __syncthreads();

    // center fp8 fragment image (8 KB/tile), raw values (scale via MFMA)
    {
      char* img = ws + OFF_CIMG + (size_t)tile * 8192;
#pragma unroll
      for (int i = 0; i < 2; ++i) {
        int q = i * 256 + t;          // 0..511
        int fid = q >> 6;             // 0..7 = (ct*2+ks2)*2+half
        int lane = q & 63;
        int ct = fid >> 2, ks2 = (fid >> 1) & 1, half = fid & 1;
        int c = tile * BN + ct * 32 + (lane & 31);
        int k0 = ks2 * 64 + (lane >> 5) * 32 + half * 16;
        float v[16];
        if (c < NC) {
          *(float4*)&v[0] = *(const float4*)(cent + (size_t)c * DD + k0);
          *(float4*)&v[4] = *(const float4*)(cent + (size_t)c * DD + k0 + 4);
          *(float4*)&v[8] = *(const float4*)(cent + (size_t)c * DD + k0 + 8);
          *(float4*)&v[12] = *(const float4*)(cent + (size_t)c * DD + k0 + 12);
        } else {
#pragma unroll
          for (int j = 0; j < 16; ++j) v[j] = 0.f;
        }
        *(uint4*)(img + fid * 1024 + lane * 16) = fp8x16(v, 1.0f);
      }
    }

    // W' fragments, lane-major: group gg covers c-local gg*16..+15;
    // lane l (j=l&31, hi=l>>5) holds W'[j][gg*16 + hi*8 + 0..7]
    {
      const int l = t & 63, gg = t >> 6;
      const int j = l & 31, hi = l >> 5;
      const int clbase = gg * 16 + hi * 8;
      unsigned d[4];
#pragma unroll
      for (int i = 0; i < 4; ++i) {
        int cl0 = clbase + 2 * i;
        int c0 = tile * BN + cl0;
        float w0 = 0.f, w1 = 0.f;
        if (j < NO) {
          if (c0 < NC) w0 = w[(size_t)c0 * NO + j] * sNF[cl0];
          if (c0 + 1 < NC) w1 = w[(size_t)(c0 + 1) * NO + j] * sNF[cl0 + 1];
        }
        d[i] = pk_bf16(w0, w1);
      }
      *(uint4*)(ws + OFF_WIMG + (size_t)tile * 4096 + t * 16) =
          make_uint4(d[0], d[1], d[2], d[3]);
    }
  }
}

// ---------------- main MFMA kernel ------------------------------------------

__device__ __forceinline__ void gld16(const char* g, const char* l) {
  __builtin_amdgcn_global_load_lds(
      (const __attribute__((address_space(1))) unsigned int*)g,
      (__attribute__((address_space(3))) unsigned int*)l, 16, 0, 0);
}

__device__ __forceinline__ short8 gload16(const char* p) {
  short8 r;
  asm volatile("global_load_dwordx4 %0, %1, off" : "=v"(r) : "v"(p));
  return r;
}
__device__ __forceinline__ i32x4 gload16i(const char* p) {
  i32x4 r;
  asm volatile("global_load_dwordx4 %0, %1, off" : "=v"(r) : "v"(p));
  return r;
}

__device__ __forceinline__ unsigned cvtpk(float lo, float hi2) {
  unsigned r;
  asm volatile("v_cvt_pk_bf16_f32 %0, %1, %2" : "=v"(r) : "v"(lo), "v"(hi2));
  return r;
}
__device__ __forceinline__ void swap32(unsigned& a, unsigned& b) {
  asm volatile("v_permlane32_swap_b32 %0, %1" : "+v"(a), "+v"(b));
}
__device__ __forceinline__ short8 mk8(unsigned a, unsigned b, unsigned c, unsigned d) {
  union { unsigned u[4]; short8 s; } z;
  z.u[0] = a; z.u[1] = b; z.u[2] = c; z.u[3] = d;
  return z.s;
}
__device__ __forceinline__ i32x8 cat8(i32x4 lo, i32x4 hi) {
  union { i32x4 h[2]; i32x8 w; } z;
  z.h[0] = lo; z.h[1] = hi;
  return z.w;
}

// exp2 + pack + permlane: acc (32x32 S^T quadrant) -> two PV A-fragments
__device__ __forceinline__ void pack32(const f32x16 acc, short8& pE, short8& pO) {
  float p[16];
#pragma unroll
  for (int r = 0; r < 16; ++r) p[r] = __builtin_amdgcn_exp2f(acc[r]);
  unsigned a0 = cvtpk(p[0], p[1]);
  unsigned a1 = cvtpk(p[2], p[3]);
  unsigned a2 = cvtpk(p[4], p[5]);
  unsigned a3 = cvtpk(p[6], p[7]);
  unsigned b0 = cvtpk(p[8], p[9]);
  unsigned b1 = cvtpk(p[10], p[11]);
  unsigned b2 = cvtpk(p[12], p[13]);
  unsigned b3 = cvtpk(p[14], p[15]);
  swap32(a0, a2);
  swap32(a1, a3);
  swap32(b0, b2);
  swap32(b1, b3);
  pE = mk8(a0, a1, a2, a3);
  pO = mk8(b0, b1, b2, b3);
}

__global__ void __launch_bounds__(256, 3) eigenpro_mfma(
    const char* __restrict__ ws, float* __restrict__ out) {
  __shared__ int4 sB[3][512];  // 3 x 8 KB fp8 center tile (24 KB)

  const int t = threadIdx.x;
  const int lane = t & 63;
  const int wid = t >> 6;
  const int l31 = lane & 31;
  const int hi = lane >> 5;

  const int chunk = blockIdx.x % NCHUNK;
  const int mb = blockIdx.x / NCHUNK;

  const char* cimg = ws + OFF_CIMG;
  const char* wimg = ws + OFF_WIMG;
  const float* xs = (const float*)(ws + OFF_XSC);

  // 782 = 14*33 + 10*32
  const int t0 = chunk * 32 + (chunk < 14 ? chunk : 14);
  const int nt = 32 + (chunk < 14 ? 1 : 0);

  // prologue: x fp8 fragments (8 gloads), then first center tile DMA (2)
  i32x8 xf[2][2];
#pragma unroll
  for (int mf = 0; mf < 2; ++mf) {
    const char* xg =
        ws + OFF_XIMG + (size_t)(mb * 8 + wid * 2 + mf) * 4096 + lane * 16;
    i32x4 h[4];
#pragma unroll
    for (int fh = 0; fh < 4; ++fh) h[fh] = gload16i(xg + fh * 1024);
    xf[mf][0] = cat8(h[0], h[1]);
    xf[mf][1] = cat8(h[2], h[3]);
  }
  __builtin_amdgcn_sched_barrier(0);
  {
    const char* cg = cimg + (size_t)t0 * 8192 + wid * 1024 + lane * 16;
    const char* cl = (const char*)&sB[0][0] + wid * 1024;
    gld16(cg, cl);
    gld16(cg + 4096, cl + 4096);
  }
  asm volatile("s_waitcnt vmcnt(2)" ::: "memory");  // xf ready; tile-0 DMA rolls
  __builtin_amdgcn_sched_barrier(0);

  const f32x16 zero16 = {0.f, 0.f, 0.f, 0.f, 0.f, 0.f, 0.f, 0.f,
                         0.f, 0.f, 0.f, 0.f, 0.f, 0.f, 0.f, 0.f};
  f32x16 pv0 = zero16, pv1 = zero16;

  int cur = 0;
#pragma unroll 1
  for (int it = 0; it < nt; ++it) {
    const int nxt = (cur == 2) ? 0 : cur + 1;
    const char* Bt = (const char*)&sB[cur][0];

    // W'(cur tile) -> regs, issued FIRST (FIFO: retires before next-tile DMA)
    const char* wg = wimg + (size_t)(t0 + it) * 4096 + lane * 16;
    short8 wfr[4];
    wfr[0] = gload16(wg);
    wfr[1] = gload16(wg + 1024);
    wfr[2] = gload16(wg + 2048);
    wfr[3] = gload16(wg + 3072);
    __builtin_amdgcn_sched_barrier(0);  // pin W-before-DMA issue order

    const int has_next = (it + 1 < nt);
    if (has_next) {
      // 3-buffer: write target 2 tiles from any reader -> no front barrier
      const char* cg = cimg + (size_t)(t0 + it + 1) * 8192 + wid * 1024 + lane * 16;
      const char* cl = (const char*)&sB[nxt][0] + wid * 1024;
      gld16(cg, cl);
      gld16(cg + 4096, cl + 4096);
      asm volatile("s_waitcnt vmcnt(6)" ::: "memory");  // cur-tile DMA done
    } else {
      asm volatile("s_waitcnt vmcnt(4)" ::: "memory");
    }
    __builtin_amdgcn_s_barrier();  // cur tile staged for all waves
    __builtin_amdgcn_sched_barrier(0);

#pragma unroll
    for (int ct = 0; ct < 2; ++ct) {
      // QK^T (S^T): MX-FP8 K=64, scale_a=1.0, scale_b=2^-4 (exact S2G fold)
      f32x16 acc0 = zero16, acc1 = zero16;
#pragma unroll
      for (int ks2 = 0; ks2 < 2; ++ks2) {
        const char* fb = Bt + ((ct * 2 + ks2) * 2) * 1024 + lane * 16;
        i32x4 lo = *(const i32x4*)fb;
        i32x4 hi4 = *(const i32x4*)(fb + 1024);
        i32x8 ca = cat8(lo, hi4);
        acc0 = __builtin_amdgcn_mfma_scale_f32_32x32x64_f8f6f4(
            ca, xf[0][ks2], acc0, 0, 0, 0, SCALE_ONE, 0, SCALE_B16);
        acc1 = __builtin_amdgcn_mfma_scale_f32_32x32x64_f8f6f4(
            ca, xf[1][ks2], acc1, 0, 0, 0, SCALE_ONE, 0, SCALE_B16);
      }

      short8 paE0, paO0, paE1, paO1;
      pack32(acc0, paE0, paO0);
      pack32(acc1, paE1, paO1);

      if (ct == 0) {
        if (has_next) {
          asm volatile("s_waitcnt vmcnt(2)" ::: "memory");  // W frags ready
        } else {
          asm volatile("s_waitcnt vmcnt(0)" ::: "memory");
        }
        __builtin_amdgcn_sched_barrier(0);  // rule-18: no wfr-use hoist
      }
      pv0 = __builtin_amdgcn_mfma_f32_32x32x16_bf16(paE0, wfr[2 * ct], pv0, 0, 0, 0);
      pv1 = __builtin_amdgcn_mfma_f32_32x32x16_bf16(paE1, wfr[2 * ct], pv1, 0, 0, 0);
      pv0 = __builtin_amdgcn_mfma_f32_32x32x16_bf16(paO0, wfr[2 * ct + 1], pv0, 0, 0, 0);
      pv1 = __builtin_amdgcn_mfma_f32_32x32x16_bf16(paO1, wfr[2 * ct + 1], pv1, 0, 0, 0);
    }
    cur = nxt;
  }

  // epilogue: out[m][j] += pv * exp2(-g'*|x_m|^2)
  if (l31 < NO) {
#pragma unroll
    for (int r = 0; r < 16; ++r) {
      int mloc = (r & 3) + 8 * (r >> 2) + 4 * hi;
      int m0 = mb * 256 + wid * 64 + mloc;
      atomicAdd(&out[(size_t)m0 * NO + l31], pv0[r] * xs[m0]);
      atomicAdd(&out[(size_t)(m0 + 32) * NO + l31], pv1[r] * xs[m0 + 32]);
    }
  }
}

// ---------------- fallback path (round-1, passing) --------------------------

__global__ void eigenpro_sqnorm(const float* __restrict__ x,
                                const float* __restrict__ cent,
                                float* __restrict__ ws) {
  int i = blockIdx.x * blockDim.x + threadIdx.x;
  if (i >= NX + NC) return;
  const float* row = (i < NX) ? (x + (size_t)i * DD) : (cent + (size_t)(i - NX) * DD);
  const float4* r4 = (const float4*)row;
  float s = 0.f;
#pragma unroll
  for (int k = 0; k < DD / 4; ++k) {
    float4 v = r4[k];
    s += v.x * v.x + v.y * v.y + v.z * v.z + v.w * v.w;
  }
  ws[i] = -GLOG2E * s;
}

__device__ __forceinline__ void stage_tile8(const float* __restrict__ src, int nrows,
                                            short* dst, int t) {
  int col4 = t & 31;
  int rb = t >> 5;
#pragma unroll
  for (int i = 0; i < 16; ++i) {
    int row = rb + 8 * i;
    float4 v = make_float4(0.f, 0.f, 0.f, 0.f);
    if (row < nrows) v = *(const float4*)(src + (size_t)row * DD + col4 * 4);
    unsigned lo = pk_bf16(v.x, v.y), hi = pk_bf16(v.z, v.w);
    char* p = (char*)dst + row * 256 + ((col4 * 8) ^ ((row & 7) << 4));
    *(uint2*)p = make_uint2(lo, hi);
  }
}

__device__ __forceinline__ short8 ld_frag8(const short* base, int row, int kbyte) {
  const char* p = (const char*)base + row * 256 + (kbyte ^ ((row & 7) << 4));
  return *(const short8*)p;
}

__global__ void __launch_bounds__(256, 2) eigenpro_main_fb(
    const float* __restrict__ x, const float* __restrict__ cent,
    const float* __restrict__ w, const float* __restrict__ ws2,
    float* __restrict__ out) {
  __shared__ short sA[128 * DD];
  __shared__ short sBP[128 * DD];
  __shared__ short sWt[16 * 128];
  __shared__ float sC2[128];

  const int t = threadIdx.x;
  const int lane = t & 63;
  const int wid = t >> 6;
  const int l15 = lane & 15;
  const int g = lane >> 4;

  const int chunk = blockIdx.x & 7;
  const int mb = blockIdx.x >> 3;
  const int m0 = mb * 128;
  const int wrow0 = wid * 32;

  const float* ws_x2 = ws2;
  const float* ws_c2 = ws2 + NX;

  stage_tile8(x + (size_t)m0 * DD, 128, sA, t);

  float u[2][4];
#pragma unroll
  for (int mf = 0; mf < 2; ++mf)
#pragma unroll
    for (int r = 0; r < 4; ++r)
      u[mf][r] = ws_x2[m0 + wrow0 + mf * 16 + 4 * g + r];

  const f32x4 zero4 = {0.f, 0.f, 0.f, 0.f};
  f32x4 pv[2];
  pv[0] = zero4;
  pv[1] = zero4;

  const int nt128 = 391;
  const int tp = 49;
  const int t0 = chunk * tp;
  const int t1 = (t0 + tp < nt128) ? (t0 + tp) : nt128;

  for (int tile = t0; tile < t1; ++tile) {
    const int c0 = tile * 128;
    int nrows = NC - c0; if (nrows > 128) nrows = 128;

    __syncthreads();
    stage_tile8(cent + (size_t)c0 * DD, nrows, sBP, t);
    if (t < 128) {
      int c = c0 + t;
      sC2[t] = (c < NC) ? ws_c2[c] : -3.0e38f;
      float wrow[NO];
#pragma unroll
      for (int j = 0; j < NO; ++j) wrow[j] = (c < NC) ? w[(size_t)c * NO + j] : 0.f;
#pragma unroll
      for (int j = 0; j < 16; ++j) {
        unsigned short h = (j < NO && c < NC) ? bf16_1(wrow[j]) : (unsigned short)0;
        *(short*)((char*)sWt + j * 256 + ((2 * t) ^ ((j & 7) << 4))) = (short)h;
      }
    }
    __syncthreads();

    float v[8];
#pragma unroll
    for (int nf = 0; nf < 8; ++nf) v[nf] = sC2[nf * 16 + l15];

    short8 a[2][4];
#pragma unroll
    for (int mf = 0; mf < 2; ++mf)
#pragma unroll
      for (int ks = 0; ks < 4; ++ks)
        a[mf][ks] = ld_frag8(sA, wrow0 + mf * 16 + l15, ks * 64 + g * 16);

    f32x4 acc[2][8];
#pragma unroll
    for (int mf = 0; mf < 2; ++mf)
#pragma unroll
      for (int nf = 0; nf < 8; ++nf) acc[mf][nf] = zero4;

#pragma unroll
    for (int nf = 0; nf < 8; ++nf) {
#pragma unroll
      for (int ks = 0; ks < 4; ++ks) {
        short8 b = ld_frag8(sBP, nf * 16 + l15, ks * 64 + g * 16);
        acc[0][nf] = __builtin_amdgcn_mfma_f32_16x16x32_bf16(a[0][ks], b, acc[0][nf], 0, 0, 0);
        acc[1][nf] = __builtin_amdgcn_mfma_f32_16x16x32_bf16(a[1][ks], b, acc[1][nf], 0, 0, 0);
      }
    }

    __syncthreads();

#pragma unroll
    for (int mf = 0; mf < 2; ++mf) {
#pragma unroll
      for (int nf = 0; nf < 8; ++nf) {
#pragma unroll
        for (int r = 0; r < 4; ++r) {
          float s = acc[mf][nf][r];
          float arg = fmaf(s, 2.f * GAMMA * LOG2E, u[mf][r] + v[nf]);
          arg = fminf(arg, 0.f);
          float p = __builtin_amdgcn_exp2f(arg);
          int mrow = wrow0 + mf * 16 + 4 * g + r;
          *(short*)((char*)sBP + mrow * 256 + ((2 * (nf * 16 + l15)) ^ ((mrow & 7) << 4))) =
              (short)bf16_1(p);
        }
      }
    }
    __syncthreads();

#pragma unroll
    for (int ks = 0; ks < 4; ++ks) {
      short8 bw = ld_frag8(sWt, l15, ks * 64 + g * 16);
#pragma unroll
      for (int mf = 0; mf < 2; ++mf) {
        short8 pa = ld_frag8(sBP, wrow0 + mf * 16 + l15, ks * 64 + g * 16);
        pv[mf] = __builtin_amdgcn_mfma_f32_16x16x32_bf16(pa, bw, pv[mf], 0, 0, 0);
      }
    }
  }

  if (l15 < NO) {
#pragma unroll
    for (int mf = 0; mf < 2; ++mf) {
#pragma unroll
      for (int r = 0; r < 4; ++r) {
        int m = m0 + wrow0 + mf * 16 + 4 * g + r;
        atomicAdd(&out[(size_t)m * NO + l15], pv[mf][r]);
      }
    }
  }
}

// ---------------- launch ----------------------------------------------------

extern "C" void kernel_launch(void* const* d_in, const int* in_sizes, int n_in,
                              void* d_out, int out_size, void* d_ws, size_t ws_size,
                              hipStream_t stream) {
  const float* x = (const float*)d_in[0];
  const float* cent = (const float*)d_in[1];
  const float* w = (const float*)d_in[2];
  float* out = (float*)d_out;

  hipMemsetAsync(d_out, 0, (size_t)out_size * sizeof(float), stream);

  if (ws_size >= WS_NEED) {
    pre_all<<<64 + NTILES, 256, 0, stream>>>(x, cent, w, (char*)d_ws);
    eigenpro_mfma<<<GRID_MAIN, 256, 0, stream>>>((const char*)d_ws, out);
  } else {
    float* ws = (float*)d_ws;
    int nrows = NX + NC;
    eigenpro_sqnorm<<<(nrows + 255) / 256, 256, 0, stream>>>(x, cent, ws);
    eigenpro_main_fb<<<64 * 8, 256, 0, stream>>>(x, cent, w, ws, out);
  }
}